// Round 4
// baseline (755.555 us; speedup 1.0000x reference)
//
#include <hip/hip_runtime.h>
#include <stdint.h>

#define CONF_T 0.01f
#define NMS_T  0.45f
#define M_TOP  200
#define SM_ROWS 256   // rows per softmax block; LDS = 256*81*4 = 82944 B -> 1 block/CU
#define TK_BS  512    // topk block size
#define N_MAX  32768  // anchors per row (problem-fixed; LDS key cache sized to this)

__device__ __forceinline__ uint32_t fkey(float f) {
    uint32_t u = __float_as_uint(f);
    return (u & 0x80000000u) ? ~u : (u | 0x80000000u);
}
__device__ __forceinline__ float fkey_inv(uint32_t k) {
    uint32_t u = (k & 0x80000000u) ? (k & 0x7FFFFFFFu) : ~k;
    return __uint_as_float(u);
}

// Wave-aggregated histogram add: one atomicAdd per DISTINCT bin per wave
// instead of one serialized LDS RMW per lane. Same-address LDS atomics
// serialize at the DS unit (~6 cyc each) -- with ~6 distinct bins per wave
// this is ~10x fewer serialized ops.
__device__ __forceinline__ void hist_add(uint32_t* hist, uint32_t bin, bool pred) {
    unsigned long long remaining = __ballot(pred);
    int lane = threadIdx.x & 63;
    while (remaining) {
        int leader = __ffsll(remaining) - 1;
        uint32_t lbin = __shfl(bin, leader);
        unsigned long long match = __ballot(pred && (bin == lbin));
        if (lane == leader) atomicAdd(&hist[lbin], (uint32_t)__popcll(match));
        remaining &= ~match;
    }
}

// ---------------- Kernel A: decode boxes ----------------
__global__ __launch_bounds__(256) void decode_kernel(
        const float* __restrict__ loc, const float* __restrict__ dbox,
        float* __restrict__ boxes, int B, int N) {
    int i = blockIdx.x * blockDim.x + threadIdx.x;
    if (i >= B * N) return;
    int n = i % N;
    float4 l = ((const float4*)loc)[i];
    float4 d = ((const float4*)dbox)[n];
    float cx = d.x + (l.x * 0.1f) * d.z;
    float cy = d.y + (l.y * 0.1f) * d.w;
    float w  = d.z * expf(l.z * 0.2f);
    float h  = d.w * expf(l.w * 0.2f);
    float x1 = cx - w * 0.5f, y1 = cy - h * 0.5f;
    float x2 = x1 + w, y2 = y1 + h;
    float4 o;
    o.x = fminf(fmaxf(x1, 0.f), 1.f);
    o.y = fminf(fmaxf(y1, 0.f), 1.f);
    o.z = fminf(fmaxf(x2, 0.f), 1.f);
    o.w = fminf(fmaxf(y2, 0.f), 1.f);
    ((float4*)boxes)[i] = o;
}

// ---------------- Kernel B: softmax + transpose (LDS-staged, coalesced) ----------------
__global__ __launch_bounds__(256) void softmax_kernel(
        const float* __restrict__ conf, float* __restrict__ sc,
        int B, int N, int C) {
    __shared__ float rows[SM_ROWS * 81];
    int tid = threadIdx.x;
    int BN = B * N;
    long long r0 = (long long)blockIdx.x * SM_ROWS;
    int nrows = BN - (int)r0; if (nrows > SM_ROWS) nrows = SM_ROWS;
    int totalf = nrows * 81;
    const float* g = conf + r0 * 81;
    int total4 = totalf >> 2;
    const float4* g4 = (const float4*)g;
    float4* l4 = (float4*)rows;
    for (int i = tid; i < total4; i += 256) l4[i] = g4[i];
    for (int i = (total4 << 2) + tid; i < totalf; i += 256) rows[i] = g[i];
    __syncthreads();
    if (tid < nrows) {
        float* p = rows + tid * 81;
        float m = p[0];
        for (int c = 1; c < 81; c++) m = fmaxf(m, p[c]);
        float s = 0.f;
        for (int c = 0; c < 81; c++) { float e = expf(p[c] - m); p[c] = e; s += e; }
        int r = (int)r0 + tid;
        int b = r / N, n = r % N;
        size_t base = ((size_t)b * (C - 1)) * N + n;
        for (int c = 1; c < 81; c++) {
            sc[base + (size_t)(c - 1) * N] = p[c] / s;
        }
    }
}

// ---------------- Kernel C: per-row exact top-200 (LDS keys + aggregated radix) --------
__global__ __launch_bounds__(TK_BS) void topk_kernel(
        const float* __restrict__ sc, const float* __restrict__ boxes,
        float* __restrict__ tk_sc, float* __restrict__ cand,
        int B, int N, int Cm1) {
    const uint32_t KEYN1 = 0x407FFFFFu;   // fkey(-1.0f)
    __shared__ uint32_t keys[N_MAX];
    __shared__ uint32_t hist[256];
    __shared__ uint32_t s_prefix, s_want;
    __shared__ uint32_t ngt, ntie;
    __shared__ float    e_val[256];
    __shared__ int      e_idx[256];
    __shared__ int      tiebuf[256];

    int row = blockIdx.x;                 // b*Cm1 + c
    int b = row / Cm1;
    int tid = threadIdx.x;
    const float* v = sc + (size_t)row * N;

    if (tid < 256) hist[tid] = 0;
    if (tid == 0) { s_prefix = 0; s_want = M_TOP; }
    __syncthreads();

    // stage: global float4 -> masked keys in LDS, with fused pass-0 histogram
    int n4 = N >> 2;
    const float4* v4 = (const float4*)v;
    uint4* k4 = (uint4*)keys;
    for (int i = tid; i < n4; i += TK_BS) {
        float4 f = v4[i];
        uint4 k;
        k.x = fkey(f.x > CONF_T ? f.x : -1.0f);
        k.y = fkey(f.y > CONF_T ? f.y : -1.0f);
        k.z = fkey(f.z > CONF_T ? f.z : -1.0f);
        k.w = fkey(f.w > CONF_T ? f.w : -1.0f);
        k4[i] = k;
        hist_add(hist, k.x >> 24, true);
        hist_add(hist, k.y >> 24, true);
        hist_add(hist, k.z >> 24, true);
        hist_add(hist, k.w >> 24, true);
    }
    for (int i = (n4 << 2) + tid; i < N; i += TK_BS) {
        float f = v[i];
        uint32_t kk = fkey(f > CONF_T ? f : -1.0f);
        keys[i] = kk;
        hist_add(hist, kk >> 24, true);
    }
    __syncthreads();
    if (tid == 0) {
        uint32_t want = s_want, cum = 0; int bin = 0;
        for (int bb = 255; bb >= 0; bb--) {
            if (cum + hist[bb] >= want) { bin = bb; break; }
            cum += hist[bb];
        }
        s_want = want - cum;
        s_prefix = (uint32_t)bin << 24;
    }
    __syncthreads();

    for (int pass = 1; pass < 4; pass++) {
        if (tid < 256) hist[tid] = 0;
        __syncthreads();
        uint32_t prefix = s_prefix;
        int shift = 24 - 8 * pass;
        uint32_t pmask = 0xFFFFFFFFu << (shift + 8);
        for (int i = tid; i < N; i += TK_BS) {
            uint32_t k = keys[i];
            bool ok = (k & pmask) == (prefix & pmask);
            hist_add(hist, (k >> shift) & 255u, ok);
        }
        __syncthreads();
        if (tid == 0) {
            uint32_t want = s_want, cum = 0; int bin = 0;
            for (int bb = 255; bb >= 0; bb--) {
                if (cum + hist[bb] >= want) { bin = bb; break; }
                cum += hist[bb];
            }
            s_want = want - cum;
            s_prefix = prefix | ((uint32_t)bin << shift);
        }
        __syncthreads();
    }
    uint32_t kth = s_prefix;
    uint32_t rfin = s_want;               // # of kth-valued elements to take
    if (tid < 256) { e_val[tid] = -1.0f; e_idx[tid] = tid; }
    if (tid == 0) { ngt = 0; ntie = 0; }
    __syncthreads();
    for (int i = tid; i < N; i += TK_BS) {
        uint32_t k = keys[i];
        if (k > kth) {
            uint32_t p = atomicAdd(&ngt, 1u);
            if (p < 256) { e_val[p] = fkey_inv(k); e_idx[p] = i; }
        } else if (k == kth && kth != KEYN1) {
            uint32_t p = atomicAdd(&ntie, 1u);
            if (p < 256) tiebuf[p] = i;
        }
    }
    __syncthreads();
    uint32_t gcount = min(ngt, (uint32_t)M_TOP);
    if (kth != KEYN1) {
        uint32_t nt = min(ntie, 256u);
        if (tid < (int)nt) {
            int mine = tiebuf[tid];
            uint32_t rk = 0;
            for (uint32_t j = 0; j < nt; j++) if (tiebuf[j] < mine) rk++;
            if (rk < rfin) {
                uint32_t slot = gcount + rk;
                if (slot < M_TOP) { e_val[slot] = fkey_inv(kth); e_idx[slot] = mine; }
            }
        }
    } else {
        if (tid >= (int)gcount && tid < M_TOP) { e_val[tid] = -1.0f; e_idx[tid] = tid; }
    }
    __syncthreads();
    // final stable ordering: (key desc, idx asc) via counting rank
    if (tid < M_TOP) {
        float mv = e_val[tid]; int mi = e_idx[tid];
        uint32_t mk = fkey(mv);
        uint32_t rk = 0;
        for (int j = 0; j < M_TOP; j++) {
            uint32_t jk = fkey(e_val[j]); int ji = e_idx[j];
            if (jk > mk || (jk == mk && ji < mi)) rk++;
        }
        size_t base = (size_t)row * M_TOP + rk;
        tk_sc[base] = mv;
        float4 bb = ((const float4*)boxes)[(size_t)b * N + mi];
        ((float4*)cand)[base] = bb;
    }
}

// ---------------- Kernel D: greedy NMS per row ----------------
__global__ __launch_bounds__(256) void nms_kernel(
        const float* __restrict__ tk_sc, const float* __restrict__ cand,
        float* __restrict__ kept) {
    int row = blockIdx.x;
    int tid = threadIdx.x;
    __shared__ float bx1[M_TOP], by1[M_TOP], bx2[M_TOP], by2[M_TOP], ar[M_TOP], ssc[M_TOP];
    __shared__ int active[M_TOP];
    __shared__ int keepf[M_TOP];
    if (tid < M_TOP) {
        size_t base = (size_t)row * M_TOP + tid;
        float4 bb = ((const float4*)cand)[base];
        bx1[tid] = bb.x; by1[tid] = bb.y; bx2[tid] = bb.z; by2[tid] = bb.w;
        ar[tid] = (bb.z - bb.x) * (bb.w - bb.y);
        float s = tk_sc[base];
        ssc[tid] = s;
        active[tid] = (s > CONF_T) ? 1 : 0;
        keepf[tid] = 0;
    }
    __syncthreads();
    for (int i = 0; i < M_TOP; i++) {
        int ki = active[i];
        __syncthreads();
        if (ki) {
            if (tid == i) keepf[i] = 1;
            if (tid < M_TOP) {
                float xx1 = fmaxf(bx1[i], bx1[tid]);
                float yy1 = fmaxf(by1[i], by1[tid]);
                float xx2 = fminf(bx2[i], bx2[tid]);
                float yy2 = fminf(by2[i], by2[tid]);
                float inter = fmaxf(xx2 - xx1, 0.f) * fmaxf(yy2 - yy1, 0.f);
                float uni = (ar[tid] - inter) + ar[i];
                float iou = inter / uni;
                if (!(iou <= NMS_T)) active[tid] = 0;   // NaN suppresses
            }
        }
        __syncthreads();
    }
    if (tid < M_TOP) {
        kept[(size_t)row * M_TOP + tid] = keepf[tid] ? ssc[tid] : 0.0f;
    }
}

// ---------------- Kernel E: global top-200 per batch ----------------
__global__ __launch_bounds__(256) void gtop_kernel(
        const float* __restrict__ kept, float* __restrict__ finsc, int Cm1) {
    const uint32_t KEY0 = 0x80000000u;    // fkey(0.0f)
    int b = blockIdx.x;
    int tid = threadIdx.x;
    const int M = Cm1 * M_TOP;            // 16000
    const float* v = kept + (size_t)b * M;
    __shared__ uint32_t hist[256];
    __shared__ uint32_t s_prefix, s_want;
    __shared__ int tiebuf[256];
    __shared__ uint32_t ntie;
    __shared__ int cutoff;

    if (tid == 0) { s_prefix = 0; s_want = M_TOP; }
    for (int pass = 0; pass < 4; pass++) {
        hist[tid] = 0;
        __syncthreads();
        uint32_t prefix = s_prefix;
        int shift = 24 - 8 * pass;
        uint32_t pmask = (pass == 0) ? 0u : (0xFFFFFFFFu << (shift + 8));
        for (int i = tid; i < M; i += 256) {
            uint32_t k = fkey(v[i]);
            bool ok = (k & pmask) == (prefix & pmask);
            hist_add(hist, (k >> shift) & 255u, ok);
        }
        __syncthreads();
        if (tid == 0) {
            uint32_t want = s_want, cum = 0; int bin = 0;
            for (int bb = 255; bb >= 0; bb--) {
                if (cum + hist[bb] >= want) { bin = bb; break; }
                cum += hist[bb];
            }
            s_want = want - cum;
            s_prefix = prefix | ((uint32_t)bin << shift);
        }
        __syncthreads();
    }
    uint32_t kth = s_prefix, rfin = s_want;
    bool tiecare = kth > KEY0;
    if (tid == 0) { ntie = 0; cutoff = -1; }
    __syncthreads();
    if (tiecare) {
        for (int i = tid; i < M; i += 256) {
            if (fkey(v[i]) == kth) { uint32_t p = atomicAdd(&ntie, 1u); if (p < 256) tiebuf[p] = i; }
        }
    }
    __syncthreads();
    uint32_t nt = min(ntie, 256u);
    if (tiecare && tid < (int)nt) {
        int mine = tiebuf[tid];
        uint32_t rk = 0;
        for (uint32_t j = 0; j < nt; j++) if (tiebuf[j] < mine) rk++;
        if (rk == rfin - 1) cutoff = mine;
    }
    __syncthreads();
    int cut = cutoff;
    for (int i = tid; i < M; i += 256) {
        float val = v[i];
        uint32_t k = fkey(val);
        bool kp = (val > 0.0f) && (k > kth || (tiecare && k == kth && i <= cut));
        finsc[(size_t)b * M + i] = kp ? val : 0.0f;
    }
}

// ---------------- Kernel F: per-class stable sort + output ----------------
__global__ __launch_bounds__(256) void out_kernel(
        const float* __restrict__ finsc, const float* __restrict__ cand,
        float* __restrict__ out, int C, int Cm1) {
    int row = blockIdx.x;   // b*Cm1 + c
    int b = row / Cm1, c = row % Cm1;
    int tid = threadIdx.x;
    __shared__ float s[M_TOP];
    if (tid < M_TOP) s[tid] = finsc[(size_t)row * M_TOP + tid];
    __syncthreads();
    if (tid < M_TOP) {
        float mv = s[tid];
        uint32_t rk = 0;
        for (int j = 0; j < M_TOP; j++) {
            float jv = s[j];
            if (jv > mv || (jv == mv && j < tid)) rk++;
        }
        size_t obase = (((size_t)(b * C + c + 1)) * M_TOP + rk) * 5;
        out[obase] = mv;
        float4 bb;
        if (mv > 0.f) bb = ((const float4*)cand)[(size_t)row * M_TOP + tid];
        else { bb.x = 0.f; bb.y = 0.f; bb.z = 0.f; bb.w = 0.f; }
        out[obase + 1] = bb.x; out[obase + 2] = bb.y;
        out[obase + 3] = bb.z; out[obase + 4] = bb.w;
    }
}

extern "C" void kernel_launch(void* const* d_in, const int* in_sizes, int n_in,
                              void* d_out, int out_size, void* d_ws, size_t ws_size,
                              hipStream_t stream) {
    const float* loc  = (const float*)d_in[0];
    const float* conf = (const float*)d_in[1];
    const float* dbox = (const float*)d_in[2];
    int N   = in_sizes[2] / 4;
    int B   = in_sizes[0] / (4 * N);
    int C   = in_sizes[1] / (B * N);
    int Cm1 = C - 1;

    char* ws = (char*)d_ws;
    size_t off = 0;
    auto alloc = [&](size_t bytes) -> char* {
        char* p = ws + off;
        off = (off + bytes + 255) & ~(size_t)255;
        return p;
    };
    float* boxes = (float*)alloc((size_t)B * N * 4 * sizeof(float));
    float* sc    = (float*)alloc((size_t)B * Cm1 * N * sizeof(float));
    float* tk_sc = (float*)alloc((size_t)B * Cm1 * M_TOP * sizeof(float));
    float* cand  = (float*)alloc((size_t)B * Cm1 * M_TOP * 4 * sizeof(float));
    float* kept  = (float*)alloc((size_t)B * Cm1 * M_TOP * sizeof(float));
    float* finsc = (float*)alloc((size_t)B * Cm1 * M_TOP * sizeof(float));

    int bn = B * N;
    decode_kernel<<<(bn + 255) / 256, 256, 0, stream>>>(loc, dbox, boxes, B, N);
    softmax_kernel<<<(bn + SM_ROWS - 1) / SM_ROWS, 256, 0, stream>>>(conf, sc, B, N, C);
    topk_kernel<<<B * Cm1, TK_BS, 0, stream>>>(sc, boxes, tk_sc, cand, B, N, Cm1);
    nms_kernel<<<B * Cm1, 256, 0, stream>>>(tk_sc, cand, kept);
    gtop_kernel<<<B, 256, 0, stream>>>(kept, finsc, Cm1);
    hipMemsetAsync(d_out, 0, (size_t)out_size * sizeof(float), stream);
    out_kernel<<<B * Cm1, 256, 0, stream>>>(finsc, cand, (float*)d_out, C, Cm1);
}

// Round 5
// 453.250 us; speedup vs baseline: 1.6670x; 1.6670x over previous
//
#include <hip/hip_runtime.h>
#include <stdint.h>

#define CONF_T 0.01f
#define NMS_T  0.45f
#define M_TOP  200
#define SM_ROWS 256   // rows per softmax block; LDS = 256*81*4 = 82944 B -> 1 block/CU
#define TK_BS  256    // topk block size (small LDS -> 8 blocks/CU)

__device__ __forceinline__ uint32_t fkey(float f) {
    uint32_t u = __float_as_uint(f);
    return (u & 0x80000000u) ? ~u : (u | 0x80000000u);
}
__device__ __forceinline__ float fkey_inv(uint32_t k) {
    uint32_t u = (k & 0x80000000u) ? (k & 0x7FFFFFFFu) : ~k;
    return __uint_as_float(u);
}

// ---------------- Kernel A: decode boxes ----------------
__global__ __launch_bounds__(256) void decode_kernel(
        const float* __restrict__ loc, const float* __restrict__ dbox,
        float* __restrict__ boxes, int B, int N) {
    int i = blockIdx.x * blockDim.x + threadIdx.x;
    if (i >= B * N) return;
    int n = i % N;
    float4 l = ((const float4*)loc)[i];
    float4 d = ((const float4*)dbox)[n];
    float cx = d.x + (l.x * 0.1f) * d.z;
    float cy = d.y + (l.y * 0.1f) * d.w;
    float w  = d.z * expf(l.z * 0.2f);
    float h  = d.w * expf(l.w * 0.2f);
    float x1 = cx - w * 0.5f, y1 = cy - h * 0.5f;
    float x2 = x1 + w, y2 = y1 + h;
    float4 o;
    o.x = fminf(fmaxf(x1, 0.f), 1.f);
    o.y = fminf(fmaxf(y1, 0.f), 1.f);
    o.z = fminf(fmaxf(x2, 0.f), 1.f);
    o.w = fminf(fmaxf(y2, 0.f), 1.f);
    ((float4*)boxes)[i] = o;
}

// ---------------- Kernel B: softmax + transpose (LDS-staged, coalesced) ----------------
__global__ __launch_bounds__(256) void softmax_kernel(
        const float* __restrict__ conf, float* __restrict__ sc,
        int B, int N, int C) {
    __shared__ float rows[SM_ROWS * 81];
    int tid = threadIdx.x;
    int BN = B * N;
    long long r0 = (long long)blockIdx.x * SM_ROWS;
    int nrows = BN - (int)r0; if (nrows > SM_ROWS) nrows = SM_ROWS;
    int totalf = nrows * 81;
    const float* g = conf + r0 * 81;
    int total4 = totalf >> 2;
    const float4* g4 = (const float4*)g;
    float4* l4 = (float4*)rows;
    for (int i = tid; i < total4; i += 256) l4[i] = g4[i];
    for (int i = (total4 << 2) + tid; i < totalf; i += 256) rows[i] = g[i];
    __syncthreads();
    if (tid < nrows) {
        float* p = rows + tid * 81;
        float m = p[0];
        for (int c = 1; c < 81; c++) m = fmaxf(m, p[c]);
        float s = 0.f;
        for (int c = 0; c < 81; c++) { float e = expf(p[c] - m); p[c] = e; s += e; }
        int r = (int)r0 + tid;
        int b = r / N, n = r % N;
        size_t base = ((size_t)b * (C - 1)) * N + n;
        for (int c = 1; c < 81; c++) {
            sc[base + (size_t)(c - 1) * N] = p[c] / s;
        }
    }
}

// ---------------- Kernel C: per-row exact top-200 ----------------
// 3-level radix select with 11/11/10-bit digits (2048-bin histograms) and a
// parallel suffix-scan for bin selection (replaces thread-0 serial scans).
// Row data is re-read from global each sweep (L2/L3-resident); LDS ~12 KB ->
// 8 blocks/CU for latency overlap. Exact ties: (key desc, idx asc).
__global__ __launch_bounds__(TK_BS) void topk_kernel(
        const float* __restrict__ sc, const float* __restrict__ boxes,
        float* __restrict__ tk_sc, float* __restrict__ cand,
        int B, int N, int Cm1) {
    const uint32_t KEYN1 = 0x407FFFFFu;   // fkey(-1.0f)
    __shared__ uint32_t hist[2048];
    __shared__ uint32_t part[256];
    __shared__ uint32_t s_prefix, s_want;
    __shared__ uint32_t ngt, ntie;
    __shared__ float    e_val[256];
    __shared__ int      e_idx[256];
    __shared__ int      tiebuf[256];

    int row = blockIdx.x;                 // b*Cm1 + c
    int b = row / Cm1;
    int tid = threadIdx.x;
    const float* v = sc + (size_t)row * N;
    const float4* v4 = (const float4*)v;
    int n4 = N >> 2;

    if (tid == 0) { s_prefix = 0; s_want = M_TOP; }
    __syncthreads();

    const int shifts[3] = {21, 10, 0};
    const int nbins_[3] = {2048, 2048, 1024};
    for (int lev = 0; lev < 3; lev++) {
        int shift = shifts[lev];
        int nb = nbins_[lev];
        uint32_t bmask = (uint32_t)nb - 1u;
        uint32_t pref  = s_prefix;        // stable: written before last barrier
        uint32_t wantv = s_want;
        for (int i = tid; i < nb; i += TK_BS) hist[i] = 0;
        __syncthreads();

        if (lev == 0) {
            for (int i = tid; i < n4; i += TK_BS) {
                float4 f = v4[i];
                uint32_t k0 = fkey(f.x > CONF_T ? f.x : -1.0f);
                uint32_t k1 = fkey(f.y > CONF_T ? f.y : -1.0f);
                uint32_t k2 = fkey(f.z > CONF_T ? f.z : -1.0f);
                uint32_t k3 = fkey(f.w > CONF_T ? f.w : -1.0f);
                atomicAdd(&hist[k0 >> 21], 1u);
                atomicAdd(&hist[k1 >> 21], 1u);
                atomicAdd(&hist[k2 >> 21], 1u);
                atomicAdd(&hist[k3 >> 21], 1u);
            }
            for (int i = (n4 << 2) + tid; i < N; i += TK_BS) {
                float f = v[i];
                atomicAdd(&hist[fkey(f > CONF_T ? f : -1.0f) >> 21], 1u);
            }
        } else {
            uint32_t pmask = 0xFFFFFFFFu << (shift + ((nb == 2048) ? 11 : 10));
            for (int i = tid; i < n4; i += TK_BS) {
                float4 f = v4[i];
                uint32_t k0 = fkey(f.x > CONF_T ? f.x : -1.0f);
                uint32_t k1 = fkey(f.y > CONF_T ? f.y : -1.0f);
                uint32_t k2 = fkey(f.z > CONF_T ? f.z : -1.0f);
                uint32_t k3 = fkey(f.w > CONF_T ? f.w : -1.0f);
                if ((k0 & pmask) == pref) atomicAdd(&hist[(k0 >> shift) & bmask], 1u);
                if ((k1 & pmask) == pref) atomicAdd(&hist[(k1 >> shift) & bmask], 1u);
                if ((k2 & pmask) == pref) atomicAdd(&hist[(k2 >> shift) & bmask], 1u);
                if ((k3 & pmask) == pref) atomicAdd(&hist[(k3 >> shift) & bmask], 1u);
            }
            for (int i = (n4 << 2) + tid; i < N; i += TK_BS) {
                float f = v[i];
                uint32_t k = fkey(f > CONF_T ? f : -1.0f);
                if ((k & pmask) == pref) atomicAdd(&hist[(k >> shift) & bmask], 1u);
            }
        }
        __syncthreads();

        // parallel suffix scan: part[t] = sum of this thread's bin chunk
        int bpt = nb >> 8;                // bins per thread (8 or 4)
        int base = tid * bpt;
        uint32_t loc = 0;
        for (int j = 0; j < bpt; j++) loc += hist[base + j];
        part[tid] = loc;
        __syncthreads();
        for (int d = 1; d < 256; d <<= 1) {
            uint32_t y = (tid + d < 256) ? part[tid + d] : 0u;
            __syncthreads();
            part[tid] += y;
            __syncthreads();
        }
        uint32_t incS = part[tid];        // sum of bins >= base
        // boundary bin: largest x with suffix_sum(x) >= want
        uint32_t run = incS - loc;        // suffix_sum(base + bpt)
        for (int j = bpt - 1; j >= 0; j--) {
            uint32_t h = hist[base + j];
            uint32_t sfx = run + h;
            if (run < wantv && sfx >= wantv) {
                s_prefix = pref | ((uint32_t)(base + j) << shift);
                s_want   = wantv - run;
            }
            run = sfx;
        }
        __syncthreads();
    }
    uint32_t kth  = s_prefix;             // exact k-th key (full 32 bits)
    uint32_t rfin = s_want;               // # of kth-valued elements to take

    if (tid < 256) { e_val[tid] = -1.0f; e_idx[tid] = tid; }
    if (tid == 0) { ngt = 0; ntie = 0; }
    __syncthreads();
    // selection sweep
    for (int i = tid; i < n4; i += TK_BS) {
        float4 f = v4[i];
        float mv[4] = { f.x > CONF_T ? f.x : -1.0f, f.y > CONF_T ? f.y : -1.0f,
                        f.z > CONF_T ? f.z : -1.0f, f.w > CONF_T ? f.w : -1.0f };
        #pragma unroll
        for (int j = 0; j < 4; j++) {
            uint32_t k = fkey(mv[j]);
            int idx = 4 * i + j;
            if (k > kth) {
                uint32_t p = atomicAdd(&ngt, 1u);
                if (p < 256) { e_val[p] = mv[j]; e_idx[p] = idx; }
            } else if (k == kth && kth != KEYN1) {
                uint32_t p = atomicAdd(&ntie, 1u);
                if (p < 256) tiebuf[p] = idx;
            }
        }
    }
    for (int i = (n4 << 2) + tid; i < N; i += TK_BS) {
        float f = v[i];
        float mv = f > CONF_T ? f : -1.0f;
        uint32_t k = fkey(mv);
        if (k > kth) {
            uint32_t p = atomicAdd(&ngt, 1u);
            if (p < 256) { e_val[p] = mv; e_idx[p] = i; }
        } else if (k == kth && kth != KEYN1) {
            uint32_t p = atomicAdd(&ntie, 1u);
            if (p < 256) tiebuf[p] = i;
        }
    }
    __syncthreads();
    uint32_t gcount = min(ngt, (uint32_t)M_TOP);
    if (kth != KEYN1) {
        uint32_t nt = min(ntie, 256u);
        if (tid < (int)nt) {
            int mine = tiebuf[tid];
            uint32_t rk = 0;
            for (uint32_t j = 0; j < nt; j++) if (tiebuf[j] < mine) rk++;
            if (rk < rfin) {
                uint32_t slot = gcount + rk;
                if (slot < M_TOP) { e_val[slot] = fkey_inv(kth); e_idx[slot] = mine; }
            }
        }
    }
    __syncthreads();
    // final stable ordering: (key desc, idx asc) via counting rank
    if (tid < M_TOP) {
        float mv = e_val[tid]; int mi = e_idx[tid];
        uint32_t mk = fkey(mv);
        uint32_t rk = 0;
        for (int j = 0; j < M_TOP; j++) {
            uint32_t jk = fkey(e_val[j]); int ji = e_idx[j];
            if (jk > mk || (jk == mk && ji < mi)) rk++;
        }
        size_t base = (size_t)row * M_TOP + rk;
        tk_sc[base] = mv;
        float4 bb = ((const float4*)boxes)[(size_t)b * N + mi];
        ((float4*)cand)[base] = bb;
    }
}

// ---------------- Kernel D: greedy NMS per row ----------------
__global__ __launch_bounds__(256) void nms_kernel(
        const float* __restrict__ tk_sc, const float* __restrict__ cand,
        float* __restrict__ kept) {
    int row = blockIdx.x;
    int tid = threadIdx.x;
    __shared__ float bx1[M_TOP], by1[M_TOP], bx2[M_TOP], by2[M_TOP], ar[M_TOP], ssc[M_TOP];
    __shared__ int active[M_TOP];
    __shared__ int keepf[M_TOP];
    if (tid < M_TOP) {
        size_t base = (size_t)row * M_TOP + tid;
        float4 bb = ((const float4*)cand)[base];
        bx1[tid] = bb.x; by1[tid] = bb.y; bx2[tid] = bb.z; by2[tid] = bb.w;
        ar[tid] = (bb.z - bb.x) * (bb.w - bb.y);
        float s = tk_sc[base];
        ssc[tid] = s;
        active[tid] = (s > CONF_T) ? 1 : 0;
        keepf[tid] = 0;
    }
    __syncthreads();
    for (int i = 0; i < M_TOP; i++) {
        int ki = active[i];
        __syncthreads();
        if (ki) {
            if (tid == i) keepf[i] = 1;
            if (tid < M_TOP) {
                float xx1 = fmaxf(bx1[i], bx1[tid]);
                float yy1 = fmaxf(by1[i], by1[tid]);
                float xx2 = fminf(bx2[i], bx2[tid]);
                float yy2 = fminf(by2[i], by2[tid]);
                float inter = fmaxf(xx2 - xx1, 0.f) * fmaxf(yy2 - yy1, 0.f);
                float uni = (ar[tid] - inter) + ar[i];
                float iou = inter / uni;
                if (!(iou <= NMS_T)) active[tid] = 0;   // NaN suppresses
            }
        }
        __syncthreads();
    }
    if (tid < M_TOP) {
        kept[(size_t)row * M_TOP + tid] = keepf[tid] ? ssc[tid] : 0.0f;
    }
}

// ---------------- Kernel E: global top-200 per batch ----------------
__global__ __launch_bounds__(256) void gtop_kernel(
        const float* __restrict__ kept, float* __restrict__ finsc, int Cm1) {
    const uint32_t KEY0 = 0x80000000u;    // fkey(0.0f)
    int b = blockIdx.x;
    int tid = threadIdx.x;
    const int M = Cm1 * M_TOP;            // 16000
    const float* v = kept + (size_t)b * M;
    __shared__ uint32_t hist[256];
    __shared__ uint32_t s_prefix, s_want;
    __shared__ int tiebuf[256];
    __shared__ uint32_t ntie;
    __shared__ int cutoff;

    if (tid == 0) { s_prefix = 0; s_want = M_TOP; }
    for (int pass = 0; pass < 4; pass++) {
        hist[tid] = 0;
        __syncthreads();
        uint32_t prefix = s_prefix;
        int shift = 24 - 8 * pass;
        for (int i = tid; i < M; i += 256) {
            uint32_t k = fkey(v[i]);
            bool ok = (pass == 0) || ((k >> (shift + 8)) == (prefix >> (shift + 8)));
            if (ok) atomicAdd(&hist[(k >> shift) & 255u], 1u);
        }
        __syncthreads();
        if (tid == 0) {
            uint32_t want = s_want, cum = 0; int bin = 0;
            for (int bb = 255; bb >= 0; bb--) {
                if (cum + hist[bb] >= want) { bin = bb; break; }
                cum += hist[bb];
            }
            s_want = want - cum;
            s_prefix = prefix | ((uint32_t)bin << shift);
        }
        __syncthreads();
    }
    uint32_t kth = s_prefix, rfin = s_want;
    bool tiecare = kth > KEY0;
    if (tid == 0) { ntie = 0; cutoff = -1; }
    __syncthreads();
    if (tiecare) {
        for (int i = tid; i < M; i += 256) {
            if (fkey(v[i]) == kth) { uint32_t p = atomicAdd(&ntie, 1u); if (p < 256) tiebuf[p] = i; }
        }
    }
    __syncthreads();
    uint32_t nt = min(ntie, 256u);
    if (tiecare && tid < (int)nt) {
        int mine = tiebuf[tid];
        uint32_t rk = 0;
        for (uint32_t j = 0; j < nt; j++) if (tiebuf[j] < mine) rk++;
        if (rk == rfin - 1) cutoff = mine;
    }
    __syncthreads();
    int cut = cutoff;
    for (int i = tid; i < M; i += 256) {
        float val = v[i];
        uint32_t k = fkey(val);
        bool kp = (val > 0.0f) && (k > kth || (tiecare && k == kth && i <= cut));
        finsc[(size_t)b * M + i] = kp ? val : 0.0f;
    }
}

// ---------------- Kernel F: per-class stable sort + output ----------------
__global__ __launch_bounds__(256) void out_kernel(
        const float* __restrict__ finsc, const float* __restrict__ cand,
        float* __restrict__ out, int C, int Cm1) {
    int row = blockIdx.x;   // b*Cm1 + c
    int b = row / Cm1, c = row % Cm1;
    int tid = threadIdx.x;
    __shared__ float s[M_TOP];
    if (tid < M_TOP) s[tid] = finsc[(size_t)row * M_TOP + tid];
    __syncthreads();
    if (tid < M_TOP) {
        float mv = s[tid];
        uint32_t rk = 0;
        for (int j = 0; j < M_TOP; j++) {
            float jv = s[j];
            if (jv > mv || (jv == mv && j < tid)) rk++;
        }
        size_t obase = (((size_t)(b * C + c + 1)) * M_TOP + rk) * 5;
        out[obase] = mv;
        float4 bb;
        if (mv > 0.f) bb = ((const float4*)cand)[(size_t)row * M_TOP + tid];
        else { bb.x = 0.f; bb.y = 0.f; bb.z = 0.f; bb.w = 0.f; }
        out[obase + 1] = bb.x; out[obase + 2] = bb.y;
        out[obase + 3] = bb.z; out[obase + 4] = bb.w;
    }
}

extern "C" void kernel_launch(void* const* d_in, const int* in_sizes, int n_in,
                              void* d_out, int out_size, void* d_ws, size_t ws_size,
                              hipStream_t stream) {
    const float* loc  = (const float*)d_in[0];
    const float* conf = (const float*)d_in[1];
    const float* dbox = (const float*)d_in[2];
    int N   = in_sizes[2] / 4;
    int B   = in_sizes[0] / (4 * N);
    int C   = in_sizes[1] / (B * N);
    int Cm1 = C - 1;

    char* ws = (char*)d_ws;
    size_t off = 0;
    auto alloc = [&](size_t bytes) -> char* {
        char* p = ws + off;
        off = (off + bytes + 255) & ~(size_t)255;
        return p;
    };
    float* boxes = (float*)alloc((size_t)B * N * 4 * sizeof(float));
    float* sc    = (float*)alloc((size_t)B * Cm1 * N * sizeof(float));
    float* tk_sc = (float*)alloc((size_t)B * Cm1 * M_TOP * sizeof(float));
    float* cand  = (float*)alloc((size_t)B * Cm1 * M_TOP * 4 * sizeof(float));
    float* kept  = (float*)alloc((size_t)B * Cm1 * M_TOP * sizeof(float));
    float* finsc = (float*)alloc((size_t)B * Cm1 * M_TOP * sizeof(float));

    int bn = B * N;
    decode_kernel<<<(bn + 255) / 256, 256, 0, stream>>>(loc, dbox, boxes, B, N);
    softmax_kernel<<<(bn + SM_ROWS - 1) / SM_ROWS, 256, 0, stream>>>(conf, sc, B, N, C);
    topk_kernel<<<B * Cm1, TK_BS, 0, stream>>>(sc, boxes, tk_sc, cand, B, N, Cm1);
    nms_kernel<<<B * Cm1, 256, 0, stream>>>(tk_sc, cand, kept);
    gtop_kernel<<<B, 256, 0, stream>>>(kept, finsc, Cm1);
    hipMemsetAsync(d_out, 0, (size_t)out_size * sizeof(float), stream);
    out_kernel<<<B * Cm1, 256, 0, stream>>>(finsc, cand, (float*)d_out, C, Cm1);
}